// Round 7
// baseline (819.196 us; speedup 1.0000x reference)
//
#include <hip/hip_runtime.h>
#include <math.h>

// Problem constants (ConvAttention: B=8, C=192, H=W=28, heads=6, ch=32, G=4)
namespace {
constexpr int kB = 8;
constexpr int kC = 192;
constexpr int kH = 28;
constexpr int kW = 28;
constexpr int kN = 784;          // kH * kW
constexpr int kHEADS = 6;
constexpr int kG = 4;
constexpr float kEPS = 1e-5f;
constexpr float kSCALE = 0.07216878364870322f;  // 192^-0.5
constexpr int kNP = 800;         // padded key rows (25 tiles of 32)
constexpr int kXP = 832;         // padded n rows for X / AO (13 tiles of 64)

constexpr int kGrid = 768;       // 3 blocks/CU; capacity at VGPR<=128 is 4/CU=1024 -> all resident
constexpr int kS1Units = 1024;   // 784 conv + 240 aux
constexpr int kS2Units = 936;    // proj tiles (13 x 3 x 24)
constexpr int kS3Units = 588;    // attn 4-wave units
constexpr int kS4Units = 312;    // outproj tiles (13 x 3 x 8)
}

typedef __attribute__((ext_vector_type(8))) short bf16x8;
typedef __attribute__((ext_vector_type(4))) float f32x4;

// f32 -> bf16 bits, round-to-nearest-even
static __device__ __forceinline__ unsigned short f2bf(float f) {
    union { float f; unsigned int u; } v; v.f = f;
    unsigned int r = v.u + 0x7fffu + ((v.u >> 16) & 1u);
    return (unsigned short)(r >> 16);
}

struct MegaArgs {
    const float *x;
    const float *dwq_w, *bnq_g, *bnq_b, *bnq_m, *bnq_v;
    const float *dwk_w, *bnk_g, *bnk_b, *bnk_m, *bnk_v;
    const float *dwv_w, *bnv_g, *bnv_b, *bnv_m, *bnv_v;
    const float *pq_w, *pk_w, *pv_w, *po_w;
    const float *pq_b, *pk_b, *pv_b, *po_b;
    unsigned short *Xq, *Xk, *Xv, *AO, *Qb, *Kb, *Vb, *Wq, *Wk, *Wv, *Wo;
    unsigned *bars;              // 3 zeroed counters (memset before launch)
    float *Y;
};

// software grid barrier: all blocks guaranteed co-resident (see kGrid note)
static __device__ __forceinline__ void gbar(unsigned* c, unsigned nb) {
    __threadfence();             // flush this thread's writes device-wide
    __syncthreads();
    if (threadIdx.x == 0) {
        __hip_atomic_fetch_add(c, 1u, __ATOMIC_ACQ_REL, __HIP_MEMORY_SCOPE_AGENT);
        while (__hip_atomic_load(c, __ATOMIC_ACQUIRE, __HIP_MEMORY_SCOPE_AGENT) < nb)
            __builtin_amdgcn_s_sleep(2);
    }
    __syncthreads();
}

// ---------------------------------------------------------------------------
// One persistent kernel, 4 stages separated by software grid barriers:
//  S1: dw3x3+BN (all 3 branches) -> Xq/Xk/Xv bf16 (b,n[kXP],c); aux blocks
//      convert weights to bf16 (Wo col-permuted) and zero all pad regions.
//  S2: 1x1 projections via MFMA -> Q,K (b,h,n[kNP],ch) bf16 (Q pre-scaled),
//      V (b,h,ch,n[kNP]) bf16.
//  S3: attention, one wave per (b,h,16-query tile): swapped QK^T MFMA,
//      in-register online softmax w/ defer-max, PV MFMA -> AO bf16.
//  S4: output projection + bias, g=4 broadcast, vectorized f32x4 stores.
// ---------------------------------------------------------------------------
__global__ __launch_bounds__(256, 4) void mega_kernel(MegaArgs A)
{
    const int NB = gridDim.x;
    const int bid = blockIdx.x;
    const int t = threadIdx.x;

    __shared__ float outs[64][68];

    const size_t XSZ = (size_t)kB * kXP * kC;

    // ================= Stage 1: dw conv + BN + prep =================
    for (int u = bid; u < kS1Units; u += NB) {
        if (u < 784) {
            if (t < 192) {
                const int c = t;
                const int b = u / 98;
                const int p0 = (u % 98) * 8;
                float wwq[9], wwk[9], wwv[9];
#pragma unroll
                for (int i = 0; i < 9; ++i) {
                    wwq[i] = A.dwq_w[c * 9 + i];
                    wwk[i] = A.dwk_w[c * 9 + i];
                    wwv[i] = A.dwv_w[c * 9 + i];
                }
                const float invq = A.bnq_g[c] * rsqrtf(A.bnq_v[c] + kEPS);
                const float addq = A.bnq_b[c] - A.bnq_m[c] * invq;
                const float invk = A.bnk_g[c] * rsqrtf(A.bnk_v[c] + kEPS);
                const float addk = A.bnk_b[c] - A.bnk_m[c] * invk;
                const float invv = A.bnv_g[c] * rsqrtf(A.bnv_v[c] + kEPS);
                const float addv = A.bnv_b[c] - A.bnv_m[c] * invv;
                const float* xb = A.x + (size_t)b * kN * kC + c;
#pragma unroll
                for (int p = 0; p < 8; ++p) {
                    const int n = p0 + p;
                    const int i = n / kW;
                    const int j = n % kW;
                    float aq = 0.f, ak = 0.f, av = 0.f;
#pragma unroll
                    for (int di = -1; di <= 1; ++di) {
                        const int ii = i + di;
                        if (ii < 0 || ii >= kH) continue;
#pragma unroll
                        for (int dj = -1; dj <= 1; ++dj) {
                            const int jj = j + dj;
                            if (jj < 0 || jj >= kW) continue;
                            const float xvl = xb[(size_t)(ii * kW + jj) * kC];
                            const int tap = (di + 1) * 3 + (dj + 1);
                            aq += xvl * wwq[tap];
                            ak += xvl * wwk[tap];
                            av += xvl * wwv[tap];
                        }
                    }
                    const size_t o = ((size_t)b * kXP + n) * kC + c;
                    A.Xq[o] = f2bf(aq * invq + addq);
                    A.Xk[o] = f2bf(ak * invk + addk);
                    A.Xv[o] = f2bf(av * invv + addv);
                }
            }
        } else {
            const int aux = (u - 784) * 256 + t;     // 0..61439
            if (aux < 36864) {
                // weight conversion, 4 elements per thread
                const int e0 = aux * 4;
                const int mat = e0 / (kC * kC);
                const int r = e0 % (kC * kC);
                if (mat < 3) {
                    const float* src = (mat == 0) ? A.pq_w : (mat == 1) ? A.pk_w : A.pv_w;
                    unsigned short* dst = (mat == 0) ? A.Wq : (mat == 1) ? A.Wk : A.Wv;
                    const f32x4 v = *(const f32x4*)&src[r];
                    ushort4 p;
                    p.x = f2bf(v[0]); p.y = f2bf(v[1]);
                    p.z = f2bf(v[2]); p.w = f2bf(v[3]);
                    *(ushort4*)&dst[r] = p;
                } else {
                    const int o = r / kC, c0 = r % kC;
                    ushort4 p;
                    unsigned short* pp = &p.x;
#pragma unroll
                    for (int e = 0; e < 4; ++e) {
                        const int c = c0 + e;
                        pp[e] = f2bf(A.po_w[o * kC + (c & 31) * kHEADS + (c >> 5)]);
                    }
                    *(ushort4*)&A.Wo[o * kC + c0] = p;
                }
            } else if (aux < 43008) {
                // K/V pad key rows [784,800) zero (16 shorts per thread)
                const int idx8 = aux - 36864;        // 0..6143
                const ushort4 z = {0, 0, 0, 0};
                if (idx8 < 3072) {
                    const int bh = idx8 / 64, k = idx8 % 64;
                    unsigned short* p = A.Kb + (size_t)bh * kNP * 32 + kN * 32 + k * 8;
                    *(ushort4*)p = z; *(ushort4*)(p + 4) = z;
                } else {
                    const int c2 = idx8 - 3072;
                    const int bh = c2 / 64, rem = c2 % 64;
                    const int ch = rem >> 1, half = rem & 1;
                    unsigned short* p = A.Vb + ((size_t)bh * 32 + ch) * kNP + kN + half * 8;
                    *(ushort4*)p = z; *(ushort4*)(p + 4) = z;
                }
            } else {
                // Xq/Xk/Xv/AO pad rows [784,832) zero (16 shorts per thread)
                const int c16 = aux - 43008;         // 0..18431
                const int arr = c16 / 4608;
                const int r = c16 % 4608;
                const int b = r / 576, rem = r % 576;
                const int row = kN + rem / 12;
                const int col16 = (rem % 12) * 16;
                unsigned short* p = A.Xq + (size_t)arr * XSZ +
                                    ((size_t)b * kXP + row) * kC + col16;
                const ushort4 z = {0, 0, 0, 0};
                *(ushort4*)(p + 0) = z; *(ushort4*)(p + 4) = z;
                *(ushort4*)(p + 8) = z; *(ushort4*)(p + 12) = z;
            }
        }
    }
    gbar(&A.bars[0], NB);

    // ================= Stage 2: 1x1 projections =================
    for (int u = bid; u < kS2Units; u += NB) {
        const int ntile = u % 13;
        const int otile = (u / 13) % 3;
        const int z = u / 39;
        const int br = z % 3;
        const int b  = z / 3;
        const unsigned short* X = (br == 0) ? A.Xq : (br == 1) ? A.Xk : A.Xv;
        const unsigned short* W = (br == 0) ? A.Wq : (br == 1) ? A.Wk : A.Wv;
        const float* bias       = (br == 0) ? A.pq_b : (br == 1) ? A.pk_b : A.pv_b;

        const int n0 = ntile * 64, o0 = otile * 64;
        const int l = t & 63, w = t >> 6;
        const int q16 = l & 15, uu = l >> 4;
        const int ob = o0 + (w >> 1) * 32;
        const int nb = n0 + (w & 1) * 32;

        f32x4 a00 = {0,0,0,0}, a01 = {0,0,0,0}, a10 = {0,0,0,0}, a11 = {0,0,0,0};
        const unsigned short* Wr0 = W + (size_t)(ob + q16) * kC + uu * 8;
        const unsigned short* Wr1 = W + (size_t)(ob + 16 + q16) * kC + uu * 8;
        const unsigned short* Xr0 = X + ((size_t)b * kXP + nb + q16) * kC + uu * 8;
        const unsigned short* Xr1 = X + ((size_t)b * kXP + nb + 16 + q16) * kC + uu * 8;
#pragma unroll
        for (int kk = 0; kk < 6; ++kk) {
            const bf16x8 wa0 = *(const bf16x8*)(Wr0 + kk * 32);
            const bf16x8 wa1 = *(const bf16x8*)(Wr1 + kk * 32);
            const bf16x8 xa0 = *(const bf16x8*)(Xr0 + kk * 32);
            const bf16x8 xa1 = *(const bf16x8*)(Xr1 + kk * 32);
            a00 = __builtin_amdgcn_mfma_f32_16x16x32_bf16(wa0, xa0, a00, 0, 0, 0);
            a01 = __builtin_amdgcn_mfma_f32_16x16x32_bf16(wa0, xa1, a01, 0, 0, 0);
            a10 = __builtin_amdgcn_mfma_f32_16x16x32_bf16(wa1, xa0, a10, 0, 0, 0);
            a11 = __builtin_amdgcn_mfma_f32_16x16x32_bf16(wa1, xa1, a11, 0, 0, 0);
        }
        const float sc = (br == 0) ? kSCALE : 1.0f;
#pragma unroll
        for (int ot = 0; ot < 2; ++ot) {
            const int obase = ob + ot * 16;
            const int hh = obase >> 5;
            const int chb = (obase & 31) + 4 * uu;
            const f32x4 bi = *(const f32x4*)&bias[obase + 4 * uu];
#pragma unroll
            for (int nt = 0; nt < 2; ++nt) {
                const f32x4 Aa = (ot == 0) ? (nt == 0 ? a00 : a01)
                                           : (nt == 0 ? a10 : a11);
                const int n = nb + nt * 16 + q16;
                if (n >= kNP) continue;
                if (br < 2) {
                    ushort4 p;
                    p.x = f2bf((Aa[0] + bi[0]) * sc);
                    p.y = f2bf((Aa[1] + bi[1]) * sc);
                    p.z = f2bf((Aa[2] + bi[2]) * sc);
                    p.w = f2bf((Aa[3] + bi[3]) * sc);
                    unsigned short* dst = ((br == 0) ? A.Qb : A.Kb) +
                        ((size_t)(b * kHEADS + hh) * kNP + n) * 32 + chb;
                    *(ushort4*)dst = p;
                } else {
                    unsigned short* dst = A.Vb +
                        ((size_t)(b * kHEADS + hh) * 32 + chb) * kNP + n;
                    dst[0 * kNP] = f2bf(Aa[0] + bi[0]);
                    dst[1 * kNP] = f2bf(Aa[1] + bi[1]);
                    dst[2 * kNP] = f2bf(Aa[2] + bi[2]);
                    dst[3 * kNP] = f2bf(Aa[3] + bi[3]);
                }
            }
        }
    }
    gbar(&A.bars[1], NB);

    // ================= Stage 3: attention =================
    for (int ub = bid; ub < kS3Units; ub += NB) {
        const int wid = ub * 4 + (t >> 6);
        const int l = t & 63;
        const int qt = wid % 49;
        const int h  = (wid / 49) % kHEADS;
        const int b  = wid / (49 * kHEADS);
        const int i0 = qt * 16;
        const int q16 = l & 15;
        const int uu = l >> 4;

        const unsigned short* Qp = A.Qb + ((size_t)(b * kHEADS + h) * kNP + i0) * 32;
        const unsigned short* Kp = A.Kb + (size_t)(b * kHEADS + h) * kNP * 32;
        const unsigned short* Vr0 = A.Vb + ((size_t)(b * kHEADS + h) * 32 + q16) * kNP;
        const unsigned short* Vr1 = Vr0 + (size_t)16 * kNP;

        const bf16x8 qa = *(const bf16x8*)(Qp + q16 * 32 + uu * 8);

        f32x4 oa0 = {0.f, 0.f, 0.f, 0.f};
        f32x4 oa1 = {0.f, 0.f, 0.f, 0.f};
        float m = -1e30f, lsum = 0.f;

        for (int tile = 0; tile < 25; ++tile) {
            const int t0 = tile * 32;
            const bf16x8 ka0 = *(const bf16x8*)(Kp + (size_t)(t0 + q16) * 32 + uu * 8);
            const bf16x8 ka1 = *(const bf16x8*)(Kp + (size_t)(t0 + 16 + q16) * 32 + uu * 8);
            f32x4 d0 = {0.f, 0.f, 0.f, 0.f};
            f32x4 d1 = {0.f, 0.f, 0.f, 0.f};
            d0 = __builtin_amdgcn_mfma_f32_16x16x32_bf16(ka0, qa, d0, 0, 0, 0);
            d1 = __builtin_amdgcn_mfma_f32_16x16x32_bf16(ka1, qa, d1, 0, 0, 0);
            if (t0 + 16 >= kN) {
                d1[0] = -1e30f; d1[1] = -1e30f; d1[2] = -1e30f; d1[3] = -1e30f;
            }
            float tm = fmaxf(fmaxf(fmaxf(d0[0], d0[1]), fmaxf(d0[2], d0[3])),
                             fmaxf(fmaxf(d1[0], d1[1]), fmaxf(d1[2], d1[3])));
            tm = fmaxf(tm, __shfl_xor(tm, 16));
            tm = fmaxf(tm, __shfl_xor(tm, 32));
            if (!__all(tm <= m + 8.0f)) {
                const float newm = fmaxf(m, tm);
                const float alpha = __expf(m - newm);
                m = newm;
                lsum *= alpha;
                const float al0 = __shfl(alpha, uu * 4 + 0);
                const float al1 = __shfl(alpha, uu * 4 + 1);
                const float al2 = __shfl(alpha, uu * 4 + 2);
                const float al3 = __shfl(alpha, uu * 4 + 3);
                oa0[0] *= al0; oa0[1] *= al1; oa0[2] *= al2; oa0[3] *= al3;
                oa1[0] *= al0; oa1[1] *= al1; oa1[2] *= al2; oa1[3] *= al3;
            }
            const float e0 = __expf(d0[0] - m), e1 = __expf(d0[1] - m);
            const float e2 = __expf(d0[2] - m), e3 = __expf(d0[3] - m);
            const float e4 = __expf(d1[0] - m), e5 = __expf(d1[1] - m);
            const float e6 = __expf(d1[2] - m), e7 = __expf(d1[3] - m);
            lsum += (((e0 + e1) + (e2 + e3)) + ((e4 + e5) + (e6 + e7)));
            union { unsigned int w[4]; bf16x8 v; } pa;
            asm("v_cvt_pk_bf16_f32 %0, %1, %2" : "=v"(pa.w[0]) : "v"(e0), "v"(e1));
            asm("v_cvt_pk_bf16_f32 %0, %1, %2" : "=v"(pa.w[1]) : "v"(e2), "v"(e3));
            asm("v_cvt_pk_bf16_f32 %0, %1, %2" : "=v"(pa.w[2]) : "v"(e4), "v"(e5));
            asm("v_cvt_pk_bf16_f32 %0, %1, %2" : "=v"(pa.w[3]) : "v"(e6), "v"(e7));
            union { ushort4 hlf[2]; bf16x8 v; } v0, v1;
            v0.hlf[0] = *(const ushort4*)(Vr0 + t0 + 4 * uu);
            v0.hlf[1] = *(const ushort4*)(Vr0 + t0 + 16 + 4 * uu);
            v1.hlf[0] = *(const ushort4*)(Vr1 + t0 + 4 * uu);
            v1.hlf[1] = *(const ushort4*)(Vr1 + t0 + 16 + 4 * uu);
            oa0 = __builtin_amdgcn_mfma_f32_16x16x32_bf16(pa.v, v0.v, oa0, 0, 0, 0);
            oa1 = __builtin_amdgcn_mfma_f32_16x16x32_bf16(pa.v, v1.v, oa1, 0, 0, 0);
        }
        lsum += __shfl_xor(lsum, 16);
        lsum += __shfl_xor(lsum, 32);
        const float rinv = 1.0f / lsum;
        const float r0 = __shfl(rinv, uu * 4 + 0);
        const float r1 = __shfl(rinv, uu * 4 + 1);
        const float r2 = __shfl(rinv, uu * 4 + 2);
        const float r3 = __shfl(rinv, uu * 4 + 3);
        unsigned short* aw = A.AO + ((size_t)b * kXP + i0 + 4 * uu) * kC + h * 32 + q16;
        aw[0 * kC + 0]  = f2bf(oa0[0] * r0);
        aw[1 * kC + 0]  = f2bf(oa0[1] * r1);
        aw[2 * kC + 0]  = f2bf(oa0[2] * r2);
        aw[3 * kC + 0]  = f2bf(oa0[3] * r3);
        aw[0 * kC + 16] = f2bf(oa1[0] * r0);
        aw[1 * kC + 16] = f2bf(oa1[1] * r1);
        aw[2 * kC + 16] = f2bf(oa1[2] * r2);
        aw[3 * kC + 16] = f2bf(oa1[3] * r3);
    }
    gbar(&A.bars[2], NB);

    // ================= Stage 4: output projection =================
    for (int u = bid; u < kS4Units; u += NB) {
        const int ntile = u % 13;
        const int otile = (u / 13) % 3;
        const int b = u / 39;
        const int n0 = ntile * 64, o0 = otile * 64;
        const int l = t & 63, w = t >> 6;
        const int q16 = l & 15, uu = l >> 4;
        const int ob = o0 + w * 16;

        f32x4 c0 = {0,0,0,0}, c1 = {0,0,0,0}, c2 = {0,0,0,0}, c3 = {0,0,0,0};
        const unsigned short* Wr = A.Wo + (size_t)(ob + q16) * kC + uu * 8;
        const unsigned short* Ar = A.AO + ((size_t)b * kXP + n0 + q16) * kC + uu * 8;
#pragma unroll
        for (int kk = 0; kk < 6; ++kk) {
            const bf16x8 a = *(const bf16x8*)(Wr + kk * 32);
            const bf16x8 x0 = *(const bf16x8*)(Ar + (size_t)0 * 16 * kC + kk * 32);
            const bf16x8 x1 = *(const bf16x8*)(Ar + (size_t)1 * 16 * kC + kk * 32);
            const bf16x8 x2 = *(const bf16x8*)(Ar + (size_t)2 * 16 * kC + kk * 32);
            const bf16x8 x3 = *(const bf16x8*)(Ar + (size_t)3 * 16 * kC + kk * 32);
            c0 = __builtin_amdgcn_mfma_f32_16x16x32_bf16(a, x0, c0, 0, 0, 0);
            c1 = __builtin_amdgcn_mfma_f32_16x16x32_bf16(a, x1, c1, 0, 0, 0);
            c2 = __builtin_amdgcn_mfma_f32_16x16x32_bf16(a, x2, c2, 0, 0, 0);
            c3 = __builtin_amdgcn_mfma_f32_16x16x32_bf16(a, x3, c3, 0, 0, 0);
        }
        const f32x4 bi = *(const f32x4*)&A.po_b[ob + 4 * uu];
#pragma unroll
        for (int nt = 0; nt < 4; ++nt) {
            const f32x4 Aa = (nt == 0) ? c0 : (nt == 1) ? c1 : (nt == 2) ? c2 : c3;
#pragma unroll
            for (int r = 0; r < 4; ++r)
                outs[w * 16 + 4 * uu + r][nt * 16 + q16] = Aa[r] + bi[r];
        }
        __syncthreads();

        const int ol = t >> 2;
        const int nq = (t & 3) * 16;
        const int nbase = n0 + nq;
        if (nbase < kN) {
            f32x4 v0 = *(const f32x4*)&outs[ol][nq + 0];
            f32x4 v1 = *(const f32x4*)&outs[ol][nq + 4];
            f32x4 v2 = *(const f32x4*)&outs[ol][nq + 8];
            f32x4 v3 = *(const f32x4*)&outs[ol][nq + 12];
            const int o = o0 + ol;
            float* yp = A.Y + (((size_t)b * kC + o) * kG) * kN + nbase;
#pragma unroll
            for (int g = 0; g < kG; ++g) {
                *(f32x4*)&yp[g * kN + 0]  = v0;
                *(f32x4*)&yp[g * kN + 4]  = v1;
                *(f32x4*)&yp[g * kN + 8]  = v2;
                *(f32x4*)&yp[g * kN + 12] = v3;
            }
        }
        __syncthreads();
    }
}

extern "C" void kernel_launch(void* const* d_in, const int* in_sizes, int n_in,
                              void* d_out, int out_size, void* d_ws, size_t ws_size,
                              hipStream_t stream) {
    unsigned short* ws = (unsigned short*)d_ws;
    const size_t XSZ = (size_t)kB * kXP * kC;           // 1,277,952
    const size_t QSZ = (size_t)kB * kHEADS * kNP * 32;  // 1,228,800

    MegaArgs a;
    a.x     = (const float*)d_in[0];
    // d_in[1]=h, d_in[2]=w (always 28; ignored)
    a.dwq_w = (const float*)d_in[3];
    a.bnq_g = (const float*)d_in[4];
    a.bnq_b = (const float*)d_in[5];
    a.bnq_m = (const float*)d_in[6];
    a.bnq_v = (const float*)d_in[7];
    a.pq_w  = (const float*)d_in[8];
    a.pq_b  = (const float*)d_in[9];
    a.dwk_w = (const float*)d_in[10];
    a.bnk_g = (const float*)d_in[11];
    a.bnk_b = (const float*)d_in[12];
    a.bnk_m = (const float*)d_in[13];
    a.bnk_v = (const float*)d_in[14];
    a.pk_w  = (const float*)d_in[15];
    a.pk_b  = (const float*)d_in[16];
    a.dwv_w = (const float*)d_in[17];
    a.bnv_g = (const float*)d_in[18];
    a.bnv_b = (const float*)d_in[19];
    a.bnv_m = (const float*)d_in[20];
    a.bnv_v = (const float*)d_in[21];
    a.pv_w  = (const float*)d_in[22];
    a.pv_b  = (const float*)d_in[23];
    a.po_w  = (const float*)d_in[24];
    a.po_b  = (const float*)d_in[25];

    // layout: [bars(64B as 32 shorts)] [Xq][Xk][Xv][AO] [Qb][Kb][Vb] [weights]
    a.bars = (unsigned*)ws;
    unsigned short* arrs = ws + 32;          // keep 16B alignment for bf16x8
    a.Xq = arrs;                             // Xq..AO contiguous (pad-zero relies on it)
    a.Xk = a.Xq + XSZ;
    a.Xv = a.Xk + XSZ;
    a.AO = a.Xv + XSZ;
    a.Qb = a.AO + XSZ;
    a.Kb = a.Qb + QSZ;
    a.Vb = a.Kb + QSZ;
    a.Wq = a.Vb + QSZ;
    a.Wk = a.Wq + kC * kC;
    a.Wv = a.Wk + kC * kC;
    a.Wo = a.Wv + kC * kC;
    a.Y  = (float*)d_out;

    hipMemsetAsync(a.bars, 0, 64, stream);   // zero barrier counters (capturable)

    mega_kernel<<<dim3(kGrid), dim3(256), 0, stream>>>(a);
}

// Round 8
// 77.704 us; speedup vs baseline: 10.5425x; 10.5425x over previous
//
#include <hip/hip_runtime.h>
#include <math.h>

// Problem constants (ConvAttention: B=8, C=192, H=W=28, heads=6, ch=32, G=4)
namespace {
constexpr int kB = 8;
constexpr int kC = 192;
constexpr int kH = 28;
constexpr int kW = 28;
constexpr int kN = 784;          // kH * kW
constexpr int kHEADS = 6;
constexpr int kG = 4;
constexpr float kEPS = 1e-5f;
constexpr float kSCALE = 0.07216878364870322f;  // 192^-0.5
constexpr int kNP = 800;         // padded key rows (25 tiles of 32)
}

typedef __attribute__((ext_vector_type(8))) short bf16x8;
typedef __attribute__((ext_vector_type(4))) float f32x4;

// f32 -> bf16 bits, round-to-nearest-even
static __device__ __forceinline__ unsigned short f2bf(float f) {
    union { float f; unsigned int u; } v; v.f = f;
    unsigned int r = v.u + 0x7fffu + ((v.u >> 16) & 1u);
    return (unsigned short)(r >> 16);
}

// ---------------------------------------------------------------------------
// K0: prep. Wq/Wk/Wv f32->bf16; Wo bf16 with column perm
// Wo'[o][h*32+c] = po_w[o][c*6+h]; zero Kb/Vb pad key rows [784,800).
// 168 blocks x 256 threads.
// ---------------------------------------------------------------------------
__global__ __launch_bounds__(256) void prep_kernel(
    const float* __restrict__ pqw, const float* __restrict__ pkw,
    const float* __restrict__ pvw, const float* __restrict__ pow_,
    unsigned short* __restrict__ Wq, unsigned short* __restrict__ Wk,
    unsigned short* __restrict__ Wv, unsigned short* __restrict__ Wo,
    unsigned short* __restrict__ Kb, unsigned short* __restrict__ Vb)
{
    const int aux = blockIdx.x * 256 + threadIdx.x;   // 0..43007
    if (aux < 36864) {
        const int e0 = aux * 4;
        const int mat = e0 / (kC * kC);
        const int r = e0 % (kC * kC);
        if (mat < 3) {
            const float* src = (mat == 0) ? pqw : (mat == 1) ? pkw : pvw;
            unsigned short* dst = (mat == 0) ? Wq : (mat == 1) ? Wk : Wv;
            const f32x4 v = *(const f32x4*)&src[r];
            ushort4 p;
            p.x = f2bf(v[0]); p.y = f2bf(v[1]); p.z = f2bf(v[2]); p.w = f2bf(v[3]);
            *(ushort4*)&dst[r] = p;
        } else {
            const int o = r / kC, c0 = r % kC;
            ushort4 p;
            unsigned short* pp = &p.x;
#pragma unroll
            for (int e = 0; e < 4; ++e) {
                const int c = c0 + e;
                pp[e] = f2bf(pow_[o * kC + (c & 31) * kHEADS + (c >> 5)]);
            }
            *(ushort4*)&Wo[o * kC + c0] = p;
        }
    } else {
        const int idx8 = aux - 36864;                 // 0..6143
        const ushort4 z = {0, 0, 0, 0};
        if (idx8 < 3072) {       // Kb pad rows: 48 bh x 64 chunks of 8
            const int bh = idx8 / 64, k = idx8 % 64;
            unsigned short* p = Kb + (size_t)bh * kNP * 32 + kN * 32 + k * 8;
            *(ushort4*)p = z; *(ushort4*)(p + 4) = z;
        } else {                 // Vb pad cols: 48 bh x 32 ch x 2 chunks of 8
            const int c2 = idx8 - 3072;
            const int bh = c2 / 64, rem = c2 % 64;
            const int ch = rem >> 1, half = rem & 1;
            unsigned short* p = Vb + ((size_t)bh * 32 + ch) * kNP + kN + half * 8;
            *(ushort4*)p = z; *(ushort4*)(p + 4) = z;
        }
    }
}

// ---------------------------------------------------------------------------
// K1: FUSED dw3x3+BN + 1x1 projection. Block = (b, 16-position tile),
// 392 blocks x 384 threads (6 waves).
// Phase A: all 3 branches' dw+BN for 16 pos x 192 ch -> LDS bf16 [3][16][200]
//          (x loads shared across branches; each output computed exactly once).
// Phase B: 36 MFMA units (br x 12 o-tiles), 6 per wave, K=192 in 6 steps.
//          Q,K -> (b,h,n[kNP],ch) bf16, Q pre-scaled; V -> (b,h,ch,n[kNP]).
// ---------------------------------------------------------------------------
__global__ __launch_bounds__(384) void dwproj_kernel(
    const float* __restrict__ x,
    const float* __restrict__ wq, const float* __restrict__ gq,
    const float* __restrict__ bq, const float* __restrict__ mq,
    const float* __restrict__ vq,
    const float* __restrict__ wk, const float* __restrict__ gk,
    const float* __restrict__ bk, const float* __restrict__ mk,
    const float* __restrict__ vk,
    const float* __restrict__ wv, const float* __restrict__ gv,
    const float* __restrict__ bv, const float* __restrict__ mv,
    const float* __restrict__ vv,
    const unsigned short* __restrict__ Wq, const unsigned short* __restrict__ Wk,
    const unsigned short* __restrict__ Wv,
    const float* __restrict__ pqb, const float* __restrict__ pkb,
    const float* __restrict__ pvb,
    unsigned short* __restrict__ Qb, unsigned short* __restrict__ Kb,
    unsigned short* __restrict__ Vb)
{
    __shared__ unsigned short Xs[3][16][200];

    const int b  = blockIdx.x / 49;
    const int n0 = (blockIdx.x % 49) * 16;
    const int t = threadIdx.x;

    // ---- Phase A: depthwise conv + BN (all 3 branches), 8 positions/thread
    {
        const int c  = t % 192;
        const int ph = t / 192;                       // 0 or 1
        float wwq[9], wwk[9], wwv[9];
#pragma unroll
        for (int i = 0; i < 9; ++i) {
            wwq[i] = wq[c * 9 + i];
            wwk[i] = wk[c * 9 + i];
            wwv[i] = wv[c * 9 + i];
        }
        const float invq = gq[c] * rsqrtf(vq[c] + kEPS);
        const float addq = bq[c] - mq[c] * invq;
        const float invk = gk[c] * rsqrtf(vk[c] + kEPS);
        const float addk = bk[c] - mk[c] * invk;
        const float invv = gv[c] * rsqrtf(vv[c] + kEPS);
        const float addv = bv[c] - mv[c] * invv;
        const float* xb = x + (size_t)b * kN * kC + c;
#pragma unroll
        for (int p = 0; p < 8; ++p) {
            const int pos = ph * 8 + p;
            const int n = n0 + pos;
            const int i = n / kW, j = n % kW;
            float aq = 0.f, ak = 0.f, av = 0.f;
#pragma unroll
            for (int di = -1; di <= 1; ++di) {
                const int ii = i + di;
                if (ii < 0 || ii >= kH) continue;
#pragma unroll
                for (int dj = -1; dj <= 1; ++dj) {
                    const int jj = j + dj;
                    if (jj < 0 || jj >= kW) continue;
                    const float xvl = xb[(size_t)(ii * kW + jj) * kC];
                    const int tap = (di + 1) * 3 + (dj + 1);
                    aq += xvl * wwq[tap];
                    ak += xvl * wwk[tap];
                    av += xvl * wwv[tap];
                }
            }
            Xs[0][pos][c] = f2bf(aq * invq + addq);
            Xs[1][pos][c] = f2bf(ak * invk + addk);
            Xs[2][pos][c] = f2bf(av * invv + addv);
        }
    }
    __syncthreads();

    // ---- Phase B: projection MFMA, 6 units per wave
    const int w = t >> 6, l = t & 63, q16 = l & 15, u = l >> 4;
#pragma unroll
    for (int k6 = 0; k6 < 6; ++k6) {
        const int unit = w * 6 + k6;
        const int br = unit / 12;
        const int ob = (unit % 12) * 16;
        const unsigned short* W = (br == 0) ? Wq : (br == 1) ? Wk : Wv;
        const float* bias       = (br == 0) ? pqb : (br == 1) ? pkb : pvb;

        f32x4 acc = {0.f, 0.f, 0.f, 0.f};
        const unsigned short* Wr = W + (size_t)(ob + q16) * kC + u * 8;
#pragma unroll
        for (int kk = 0; kk < 6; ++kk) {
            const bf16x8 wa = *(const bf16x8*)(Wr + kk * 32);
            const bf16x8 xa = *(const bf16x8*)&Xs[br][q16][u * 8 + kk * 32];
            acc = __builtin_amdgcn_mfma_f32_16x16x32_bf16(wa, xa, acc, 0, 0, 0);
        }
        const int hh = ob >> 5;
        const int ch0 = (ob & 31) + 4 * u;
        const f32x4 bi = *(const f32x4*)&bias[ob + 4 * u];
        const int n = n0 + q16;
        if (br < 2) {
            const float sc = (br == 0) ? kSCALE : 1.0f;
            ushort4 p;
            p.x = f2bf((acc[0] + bi[0]) * sc);
            p.y = f2bf((acc[1] + bi[1]) * sc);
            p.z = f2bf((acc[2] + bi[2]) * sc);
            p.w = f2bf((acc[3] + bi[3]) * sc);
            unsigned short* dst = ((br == 0) ? Qb : Kb) +
                ((size_t)(b * kHEADS + hh) * kNP + n) * 32 + ch0;
            *(ushort4*)dst = p;
        } else {
            unsigned short* dst = Vb +
                ((size_t)(b * kHEADS + hh) * 32 + ch0) * kNP + n;
            dst[0 * kNP] = f2bf(acc[0] + bi[0]);
            dst[1 * kNP] = f2bf(acc[1] + bi[1]);
            dst[2 * kNP] = f2bf(acc[2] + bi[2]);
            dst[3 * kNP] = f2bf(acc[3] + bi[3]);
        }
    }
}

// ---------------------------------------------------------------------------
// K2: FUSED attention + output projection. Block = (b, 16-query tile),
// 392 blocks x 384 threads; wave h = head h.
// Attn: swapped QK^T MFMA, in-register online softmax (defer-max THR=8),
// PV MFMA; AO -> LDS [16][200] bf16 (cols h*32+c). syncthreads.
// Outproj: 12 o-tile units (2/wave), Wo' bf16 A-frags, bias, g=4 broadcast.
// ---------------------------------------------------------------------------
__global__ __launch_bounds__(384) void attnout_kernel(
    const unsigned short* __restrict__ Qbf, const unsigned short* __restrict__ Kbf,
    const unsigned short* __restrict__ Vbf, const unsigned short* __restrict__ Wo,
    const float* __restrict__ pob, float* __restrict__ Y)
{
    __shared__ unsigned short AOs[16][200];

    const int b  = blockIdx.x / 49;
    const int i0 = (blockIdx.x % 49) * 16;
    const int t = threadIdx.x;
    const int h = t >> 6;            // wave = head
    const int l = t & 63;
    const int q16 = l & 15;
    const int u = l >> 4;

    {
        const unsigned short* Qp = Qbf + ((size_t)(b * kHEADS + h) * kNP + i0) * 32;
        const unsigned short* Kp = Kbf + (size_t)(b * kHEADS + h) * kNP * 32;
        const unsigned short* Vr0 = Vbf + ((size_t)(b * kHEADS + h) * 32 + q16) * kNP;
        const unsigned short* Vr1 = Vr0 + (size_t)16 * kNP;

        const bf16x8 qa = *(const bf16x8*)(Qp + q16 * 32 + u * 8);

        f32x4 oa0 = {0.f, 0.f, 0.f, 0.f};
        f32x4 oa1 = {0.f, 0.f, 0.f, 0.f};
        float m = -1e30f, lsum = 0.f;

        for (int tile = 0; tile < 25; ++tile) {
            const int t0 = tile * 32;
            const bf16x8 ka0 = *(const bf16x8*)(Kp + (size_t)(t0 + q16) * 32 + u * 8);
            const bf16x8 ka1 = *(const bf16x8*)(Kp + (size_t)(t0 + 16 + q16) * 32 + u * 8);
            f32x4 d0 = {0.f, 0.f, 0.f, 0.f};
            f32x4 d1 = {0.f, 0.f, 0.f, 0.f};
            d0 = __builtin_amdgcn_mfma_f32_16x16x32_bf16(ka0, qa, d0, 0, 0, 0);
            d1 = __builtin_amdgcn_mfma_f32_16x16x32_bf16(ka1, qa, d1, 0, 0, 0);
            if (t0 + 16 >= kN) {  // last tile: keys t0+16.. are zero pads -> mask
                d1[0] = -1e30f; d1[1] = -1e30f; d1[2] = -1e30f; d1[3] = -1e30f;
            }
            float tm = fmaxf(fmaxf(fmaxf(d0[0], d0[1]), fmaxf(d0[2], d0[3])),
                             fmaxf(fmaxf(d1[0], d1[1]), fmaxf(d1[2], d1[3])));
            tm = fmaxf(tm, __shfl_xor(tm, 16));
            tm = fmaxf(tm, __shfl_xor(tm, 32));
            if (!__all(tm <= m + 8.0f)) {
                const float newm = fmaxf(m, tm);
                const float alpha = __expf(m - newm);
                m = newm;
                lsum *= alpha;
                const float al0 = __shfl(alpha, u * 4 + 0);
                const float al1 = __shfl(alpha, u * 4 + 1);
                const float al2 = __shfl(alpha, u * 4 + 2);
                const float al3 = __shfl(alpha, u * 4 + 3);
                oa0[0] *= al0; oa0[1] *= al1; oa0[2] *= al2; oa0[3] *= al3;
                oa1[0] *= al0; oa1[1] *= al1; oa1[2] *= al2; oa1[3] *= al3;
            }
            const float e0 = __expf(d0[0] - m), e1 = __expf(d0[1] - m);
            const float e2 = __expf(d0[2] - m), e3 = __expf(d0[3] - m);
            const float e4 = __expf(d1[0] - m), e5 = __expf(d1[1] - m);
            const float e6 = __expf(d1[2] - m), e7 = __expf(d1[3] - m);
            lsum += (((e0 + e1) + (e2 + e3)) + ((e4 + e5) + (e6 + e7)));
            union { unsigned int w[4]; bf16x8 v; } pa;
            asm("v_cvt_pk_bf16_f32 %0, %1, %2" : "=v"(pa.w[0]) : "v"(e0), "v"(e1));
            asm("v_cvt_pk_bf16_f32 %0, %1, %2" : "=v"(pa.w[1]) : "v"(e2), "v"(e3));
            asm("v_cvt_pk_bf16_f32 %0, %1, %2" : "=v"(pa.w[2]) : "v"(e4), "v"(e5));
            asm("v_cvt_pk_bf16_f32 %0, %1, %2" : "=v"(pa.w[3]) : "v"(e6), "v"(e7));
            union { ushort4 hlf[2]; bf16x8 v; } v0, v1;
            v0.hlf[0] = *(const ushort4*)(Vr0 + t0 + 4 * u);
            v0.hlf[1] = *(const ushort4*)(Vr0 + t0 + 16 + 4 * u);
            v1.hlf[0] = *(const ushort4*)(Vr1 + t0 + 4 * u);
            v1.hlf[1] = *(const ushort4*)(Vr1 + t0 + 16 + 4 * u);
            oa0 = __builtin_amdgcn_mfma_f32_16x16x32_bf16(pa.v, v0.v, oa0, 0, 0, 0);
            oa1 = __builtin_amdgcn_mfma_f32_16x16x32_bf16(pa.v, v1.v, oa1, 0, 0, 0);
        }
        lsum += __shfl_xor(lsum, 16);
        lsum += __shfl_xor(lsum, 32);
        const float rinv = 1.0f / lsum;
        const float r0 = __shfl(rinv, u * 4 + 0);
        const float r1 = __shfl(rinv, u * 4 + 1);
        const float r2 = __shfl(rinv, u * 4 + 2);
        const float r3 = __shfl(rinv, u * 4 + 3);
        // AO -> LDS rows 4u+r, cols h*32 + {q16, 16+q16}
        AOs[4 * u + 0][h * 32 + q16] = f2bf(oa0[0] * r0);
        AOs[4 * u + 1][h * 32 + q16] = f2bf(oa0[1] * r1);
        AOs[4 * u + 2][h * 32 + q16] = f2bf(oa0[2] * r2);
        AOs[4 * u + 3][h * 32 + q16] = f2bf(oa0[3] * r3);
        AOs[4 * u + 0][h * 32 + 16 + q16] = f2bf(oa1[0] * r0);
        AOs[4 * u + 1][h * 32 + 16 + q16] = f2bf(oa1[1] * r1);
        AOs[4 * u + 2][h * 32 + 16 + q16] = f2bf(oa1[2] * r2);
        AOs[4 * u + 3][h * 32 + 16 + q16] = f2bf(oa1[3] * r3);
    }
    __syncthreads();

    // ---- output projection: 2 o-tiles per wave
#pragma unroll
    for (int k2 = 0; k2 < 2; ++k2) {
        const int ob = (h * 2 + k2) * 16;
        f32x4 acc = {0.f, 0.f, 0.f, 0.f};
        const unsigned short* Wr = Wo + (size_t)(ob + q16) * kC + u * 8;
#pragma unroll
        for (int kk = 0; kk < 6; ++kk) {
            const bf16x8 wa = *(const bf16x8*)(Wr + kk * 32);
            const bf16x8 xa = *(const bf16x8*)&AOs[q16][u * 8 + kk * 32];
            acc = __builtin_amdgcn_mfma_f32_16x16x32_bf16(wa, xa, acc, 0, 0, 0);
        }
        const f32x4 bi = *(const f32x4*)&pob[ob + 4 * u];
        const int n = i0 + q16;
#pragma unroll
        for (int r = 0; r < 4; ++r) {
            const int o = ob + 4 * u + r;
            const float val = acc[r] + bi[r];
            float* yp = Y + (((size_t)b * kC + o) * kG) * kN + n;
            yp[0 * kN] = val;
            yp[1 * kN] = val;
            yp[2 * kN] = val;
            yp[3 * kN] = val;
        }
    }
}

extern "C" void kernel_launch(void* const* d_in, const int* in_sizes, int n_in,
                              void* d_out, int out_size, void* d_ws, size_t ws_size,
                              hipStream_t stream) {
    const float* x     = (const float*)d_in[0];
    // d_in[1]=h, d_in[2]=w (always 28; ignored)
    const float* dwq_w = (const float*)d_in[3];
    const float* bnq_g = (const float*)d_in[4];
    const float* bnq_b = (const float*)d_in[5];
    const float* bnq_m = (const float*)d_in[6];
    const float* bnq_v = (const float*)d_in[7];
    const float* pq_w  = (const float*)d_in[8];
    const float* pq_b  = (const float*)d_in[9];
    const float* dwk_w = (const float*)d_in[10];
    const float* bnk_g = (const float*)d_in[11];
    const float* bnk_b = (const float*)d_in[12];
    const float* bnk_m = (const float*)d_in[13];
    const float* bnk_v = (const float*)d_in[14];
    const float* pk_w  = (const float*)d_in[15];
    const float* pk_b  = (const float*)d_in[16];
    const float* dwv_w = (const float*)d_in[17];
    const float* bnv_g = (const float*)d_in[18];
    const float* bnv_b = (const float*)d_in[19];
    const float* bnv_m = (const float*)d_in[20];
    const float* bnv_v = (const float*)d_in[21];
    const float* pv_w  = (const float*)d_in[22];
    const float* pv_b  = (const float*)d_in[23];
    const float* po_w  = (const float*)d_in[24];
    const float* po_b  = (const float*)d_in[25];

    unsigned short* ws = (unsigned short*)d_ws;
    const size_t QSZ = (size_t)kB * kHEADS * kNP * 32;  // 1,228,800
    unsigned short* Qb = ws;
    unsigned short* Kb = Qb + QSZ;
    unsigned short* Vb = Kb + QSZ;
    unsigned short* Wq = Vb + QSZ;
    unsigned short* Wk = Wq + kC * kC;
    unsigned short* Wv = Wk + kC * kC;
    unsigned short* Wo = Wv + kC * kC;

    prep_kernel<<<dim3(168), dim3(256), 0, stream>>>(
        pq_w, pk_w, pv_w, po_w, Wq, Wk, Wv, Wo, Kb, Vb);

    dwproj_kernel<<<dim3(kB * 49), dim3(384), 0, stream>>>(
        x,
        dwq_w, bnq_g, bnq_b, bnq_m, bnq_v,
        dwk_w, bnk_g, bnk_b, bnk_m, bnk_v,
        dwv_w, bnv_g, bnv_b, bnv_m, bnv_v,
        Wq, Wk, Wv, pq_b, pk_b, pv_b, Qb, Kb, Vb);

    attnout_kernel<<<dim3(kB * 49), dim3(384), 0, stream>>>(
        Qb, Kb, Vb, Wo, po_b, (float*)d_out);
}